// Round 1
// baseline (325.027 us; speedup 1.0000x reference)
//
#include <hip/hip_runtime.h>
#include <math.h>

#define NH 8
#define NN 4096
#define FF 128
#define SEG 64
#define NSEG (NN / SEG)  // 64

// K1: h_prime[h] = h @ w[h]  (fp32, LDS-staged h tile), fused per-row dots with
// a_src/a_dst producing attn_src[h,n], attn_dst[h,n].
__global__ __launch_bounds__(256) void k1_gemm(
    const float* __restrict__ h, const float* __restrict__ w,
    const float* __restrict__ a_src, const float* __restrict__ a_dst,
    float* __restrict__ hp, float* __restrict__ attn_src,
    float* __restrict__ attn_dst) {
  __shared__ float sh[32 * 129];  // 32 rows x 128 cols, padded stride 129
  const int head = blockIdx.y;
  const int r0 = blockIdx.x * 32;
  const int tid = threadIdx.x;

  // stage 32 rows of h (contiguous 4096 floats) into LDS
  const float4* hg4 = reinterpret_cast<const float4*>(h + (size_t)r0 * FF);
  #pragma unroll
  for (int it = 0; it < 4; ++it) {
    int q = tid + it * 256;  // float4 index 0..1023
    float4 v = hg4[q];
    int row = q >> 5, c4 = q & 31;
    float* dst = &sh[row * 129 + c4 * 4];
    dst[0] = v.x; dst[1] = v.y; dst[2] = v.z; dst[3] = v.w;
  }
  __syncthreads();

  const int row2 = tid >> 3;  // 0..31 (row within tile)
  const int cg = tid & 7;     // 0..7  (column group of 16)
  float acc[16];
  #pragma unroll
  for (int i = 0; i < 16; ++i) acc[i] = 0.f;

  const float4* w4 =
      reinterpret_cast<const float4*>(w) + (size_t)head * 128 * 32 + cg * 4;
  #pragma unroll 4
  for (int k = 0; k < 128; ++k) {
    float av = sh[row2 * 129 + k];
    float4 b0 = w4[k * 32 + 0];
    float4 b1 = w4[k * 32 + 1];
    float4 b2 = w4[k * 32 + 2];
    float4 b3 = w4[k * 32 + 3];
    acc[0] += av * b0.x; acc[1] += av * b0.y; acc[2] += av * b0.z; acc[3] += av * b0.w;
    acc[4] += av * b1.x; acc[5] += av * b1.y; acc[6] += av * b1.z; acc[7] += av * b1.w;
    acc[8] += av * b2.x; acc[9] += av * b2.y; acc[10] += av * b2.z; acc[11] += av * b2.w;
    acc[12] += av * b3.x; acc[13] += av * b3.y; acc[14] += av * b3.z; acc[15] += av * b3.w;
  }

  const int r = r0 + row2;
  float4* hp4 = reinterpret_cast<float4*>(hp) +
                ((size_t)(head * NN + r)) * 32 + cg * 4;
  hp4[0] = make_float4(acc[0], acc[1], acc[2], acc[3]);
  hp4[1] = make_float4(acc[4], acc[5], acc[6], acc[7]);
  hp4[2] = make_float4(acc[8], acc[9], acc[10], acc[11]);
  hp4[3] = make_float4(acc[12], acc[13], acc[14], acc[15]);

  // fused score dots: attn_src[h,r] = hp_row . a_src[h], same for dst
  const float* As = a_src + head * FF + cg * 16;
  const float* Ad = a_dst + head * FF + cg * 16;
  float sA = 0.f, sD = 0.f;
  #pragma unroll
  for (int i = 0; i < 16; ++i) {
    sA += acc[i] * As[i];
    sD += acc[i] * Ad[i];
  }
  // reduce across the 8 column-groups (lanes differing in low 3 bits)
  sA += __shfl_xor(sA, 1); sA += __shfl_xor(sA, 2); sA += __shfl_xor(sA, 4);
  sD += __shfl_xor(sD, 1); sD += __shfl_xor(sD, 2); sD += __shfl_xor(sD, 4);
  if (cg == 0) {
    attn_src[head * NN + r] = sA;
    attn_dst[head * NN + r] = sD;
  }
}

// K2: per-head bitonic sort of d = attn_dst ascending, with permutation.
__global__ __launch_bounds__(1024) void k2_sort(
    const float* __restrict__ attn_dst, float* __restrict__ dsort,
    int* __restrict__ permd) {
  __shared__ float key[NN];
  __shared__ int idx[NN];
  const int head = blockIdx.x;
  const int tid = threadIdx.x;
  for (int i = tid; i < NN; i += 1024) {
    key[i] = attn_dst[head * NN + i];
    idx[i] = i;
  }
  __syncthreads();
  for (int k = 2; k <= NN; k <<= 1) {
    for (int j = k >> 1; j > 0; j >>= 1) {
      for (int i = tid; i < NN; i += 1024) {
        int ixj = i ^ j;
        if (ixj > i) {
          float a = key[i], b = key[ixj];
          bool up = ((i & k) == 0);
          if (up ? (a > b) : (a < b)) {
            key[i] = b; key[ixj] = a;
            int t = idx[i]; idx[i] = idx[ixj]; idx[ixj] = t;
          }
        }
      }
      __syncthreads();
    }
  }
  for (int i = tid; i < NN; i += 1024) {
    dsort[head * NN + i] = key[i];
    permd[head * NN + i] = idx[i];
  }
}

// K3: per (head, 64-element segment of sorted order): partial sums of
// e^{0.2d}*hp and e^{d}*hp (feature vectors) + scalar denominators.
__global__ __launch_bounds__(128) void k3_segsum(
    const float* __restrict__ hp, const float* __restrict__ dsort,
    const int* __restrict__ permd, float* __restrict__ segs,
    float* __restrict__ segz) {
  const int head = blockIdx.y, seg = blockIdx.x, o = threadIdx.x;
  const float* dp = dsort + head * NN + seg * SEG;
  const int* pp = permd + head * NN + seg * SEG;
  const float* hph = hp + (size_t)head * NN * FF;
  float a0 = 0, a1 = 0, z0 = 0, z1 = 0;
  for (int jj = 0; jj < SEG; ++jj) {
    float dj = dp[jj];
    int m = pp[jj];
    float hv = hph[(size_t)m * FF + o];
    float e0 = expf(0.2f * dj), e1 = expf(dj);
    a0 += e0 * hv; a1 += e1 * hv;
    z0 += e0; z1 += e1;
  }
  size_t base = ((size_t)(head * NSEG + seg)) * 2 * FF;
  segs[base + o] = a0;
  segs[base + FF + o] = a1;
  if (o == 0) {
    segz[(head * NSEG + seg) * 2 + 0] = z0;
    segz[(head * NSEG + seg) * 2 + 1] = z1;
  }
}

// K4: exclusive scan of the 64 segment sums per head (checkpoints).
__global__ __launch_bounds__(128) void k4_ckpt(
    const float* __restrict__ segs, const float* __restrict__ segz,
    float* __restrict__ ckpt, float* __restrict__ ckptz) {
  const int head = blockIdx.x, o = threadIdx.x;
  float r0 = 0, r1 = 0;
  for (int k = 0; k < NSEG; ++k) {
    size_t base = ((size_t)(head * NSEG + k)) * 2 * FF;
    ckpt[base + o] = r0;
    ckpt[base + FF + o] = r1;
    r0 += segs[base + o];
    r1 += segs[base + FF + o];
  }
  if (o == 0) {
    float z0 = 0, z1 = 0;
    for (int k = 0; k < NSEG; ++k) {
      ckptz[(head * NSEG + k) * 2 + 0] = z0;
      ckptz[(head * NSEG + k) * 2 + 1] = z1;
      z0 += segz[(head * NSEG + k) * 2 + 0];
      z1 += segz[(head * NSEG + k) * 2 + 1];
    }
  }
}

// K5: materialize full inclusive prefix arrays PF[h][j][2][128] + PFz[h][j][2].
__global__ __launch_bounds__(128) void k5_prefix(
    const float* __restrict__ hp, const float* __restrict__ dsort,
    const int* __restrict__ permd, const float* __restrict__ ckpt,
    const float* __restrict__ ckptz, float* __restrict__ PF,
    float* __restrict__ PFz) {
  const int head = blockIdx.y, seg = blockIdx.x, o = threadIdx.x;
  size_t cb = ((size_t)(head * NSEG + seg)) * 2 * FF;
  float r0 = ckpt[cb + o], r1 = ckpt[cb + FF + o];
  float z0 = ckptz[(head * NSEG + seg) * 2 + 0];
  float z1 = ckptz[(head * NSEG + seg) * 2 + 1];
  const float* hph = hp + (size_t)head * NN * FF;
  for (int jj = 0; jj < SEG; ++jj) {
    int j = seg * SEG + jj;
    float dj = dsort[head * NN + j];
    int m = permd[head * NN + j];
    float hv = hph[(size_t)m * FF + o];
    float e0 = expf(0.2f * dj), e1 = expf(dj);
    r0 += e0 * hv; r1 += e1 * hv;
    z0 += e0; z1 += e1;
    size_t pb = ((size_t)(head * NN + j)) * 2 * FF;
    PF[pb + o] = r0;
    PF[pb + FF + o] = r1;
    if (o == 0) {
      PFz[(head * NN + j) * 2 + 0] = z0;
      PFz[(head * NN + j) * 2 + 1] = z1;
    }
  }
}

// K6: per output row: for each head, binary-search threshold t = #{d <= -s},
// read prefix vectors at t-1, combine the two exp branches, mean over heads.
__global__ __launch_bounds__(128) void k6_out(
    const float* __restrict__ attn_src, const float* __restrict__ dsort,
    const float* __restrict__ PF, const float* __restrict__ PFz,
    const float* __restrict__ bias, float* __restrict__ out) {
  const int n = blockIdx.x, o = threadIdx.x;
  float acc = 0.f;
  for (int head = 0; head < NH; ++head) {
    float s = attn_src[head * NN + n];
    float thresh = -s;
    const float* dp = dsort + head * NN;
    int lo = 0, hi = NN;
    while (lo < hi) {  // uniform across the block
      int mid = (lo + hi) >> 1;
      if (dp[mid] <= thresh) lo = mid + 1; else hi = mid;
    }
    int t = lo;  // count of d <= -s  (these take the 0.2-slope branch)
    size_t tb = ((size_t)(head * NN + NN - 1)) * 2 * FF;
    float TotA = PF[tb + FF + o];
    float z1tot = PFz[(head * NN + NN - 1) * 2 + 1];
    float B = 0.f, P1 = 0.f, z0p = 0.f, z1p = 0.f;
    if (t > 0) {
      size_t pb = ((size_t)(head * NN + t - 1)) * 2 * FF;
      B = PF[pb + o];
      P1 = PF[pb + FF + o];
      z0p = PFz[(head * NN + t - 1) * 2 + 0];
      z1p = PFz[(head * NN + t - 1) * 2 + 1];
    }
    float e02s = expf(0.2f * s), es = expf(s);
    float den = e02s * z0p + es * (z1tot - z1p);
    acc += (e02s * B + es * (TotA - P1)) / den;
  }
  out[(size_t)n * FF + o] = 0.125f * acc + bias[o];
}

extern "C" void kernel_launch(void* const* d_in, const int* in_sizes, int n_in,
                              void* d_out, int out_size, void* d_ws,
                              size_t ws_size, hipStream_t stream) {
  const float* h = (const float*)d_in[0];
  const float* w = (const float*)d_in[1];
  const float* a_src = (const float*)d_in[2];
  const float* a_dst = (const float*)d_in[3];
  const float* bias = (const float*)d_in[4];
  float* out = (float*)d_out;

  char* ws = (char*)d_ws;
  size_t off = 0;
  auto alloc = [&](size_t bytes) -> void* {
    void* p = ws + off;
    off += (bytes + 255) & ~(size_t)255;
    return p;
  };
  float* hp = (float*)alloc((size_t)NH * NN * FF * 4);       // 16.8 MB
  float* asrc = (float*)alloc((size_t)NH * NN * 4);
  float* adst = (float*)alloc((size_t)NH * NN * 4);
  float* dsort = (float*)alloc((size_t)NH * NN * 4);
  int* permd = (int*)alloc((size_t)NH * NN * 4);
  float* segs = (float*)alloc((size_t)NH * NSEG * 2 * FF * 4);
  float* segz = (float*)alloc((size_t)NH * NSEG * 2 * 4);
  float* ckpt = (float*)alloc((size_t)NH * NSEG * 2 * FF * 4);
  float* ckptz = (float*)alloc((size_t)NH * NSEG * 2 * 4);
  float* PF = (float*)alloc((size_t)NH * NN * 2 * FF * 4);   // 33.5 MB
  float* PFz = (float*)alloc((size_t)NH * NN * 2 * 4);
  (void)ws_size;  // requires ~52.3 MB of workspace

  k1_gemm<<<dim3(NN / 32, NH), 256, 0, stream>>>(h, w, a_src, a_dst, hp, asrc,
                                                 adst);
  k2_sort<<<NH, 1024, 0, stream>>>(adst, dsort, permd);
  k3_segsum<<<dim3(NSEG, NH), 128, 0, stream>>>(hp, dsort, permd, segs, segz);
  k4_ckpt<<<NH, 128, 0, stream>>>(segs, segz, ckpt, ckptz);
  k5_prefix<<<dim3(NSEG, NH), 128, 0, stream>>>(hp, dsort, permd, ckpt, ckptz,
                                                PF, PFz);
  k6_out<<<NN, 128, 0, stream>>>(asrc, dsort, PF, PFz, bias, out);
}

// Round 3
// 206.257 us; speedup vs baseline: 1.5758x; 1.5758x over previous
//
#include <hip/hip_runtime.h>
#include <math.h>

#define NH 8
#define NN 4096
#define FF 128
#define SEG 64
#define NSEG (NN / SEG)  // 64

// K1: hp[h] = h @ w[h] (fp32, LDS-tiled, 4x4 register tile per thread) with
// fused per-row score dots -> attn_src[h,n], attn_dst[h,n].
__global__ __launch_bounds__(256) void k1_gemm(
    const float* __restrict__ h, const float* __restrict__ w,
    const float* __restrict__ a_src, const float* __restrict__ a_dst,
    float* __restrict__ hp, float* __restrict__ attn_src,
    float* __restrict__ attn_dst) {
  __shared__ float sw[32 * 128];  // w chunk [32 k][128 c]
  __shared__ float shT[32 * 32];  // h chunk transposed [32 k][32 r], XOR-swizzled
  const int head = blockIdx.y;
  const int r0 = blockIdx.x * 32;
  const int tid = threadIdx.x;
  const int ty = tid >> 5;  // 0..7 -> rows ty*4..+3
  const int tx = tid & 31;  // 0..31 -> cols tx*4..+3

  float acc[4][4];
  #pragma unroll
  for (int i = 0; i < 4; ++i)
    #pragma unroll
    for (int j = 0; j < 4; ++j) acc[i][j] = 0.f;

  const float4* wg = reinterpret_cast<const float4*>(w + (size_t)head * 128 * 128);
  const float4* hg = reinterpret_cast<const float4*>(h);

  for (int kc = 0; kc < 4; ++kc) {
    const int k0 = kc * 32;
    __syncthreads();
    // stage w chunk: [32][128] floats, direct copy (conflict-free b128 writes)
    #pragma unroll
    for (int it = 0; it < 4; ++it) {
      int q = tid + it * 256;
      int krow = q >> 5, c4 = q & 31;
      float4 v = wg[(size_t)(k0 + krow) * 32 + c4];
      float* dst = &sw[krow * 128 + c4 * 4];
      dst[0] = v.x; dst[1] = v.y; dst[2] = v.z; dst[3] = v.w;
    }
    // stage h chunk transposed with XOR swizzle (row' = row ^ ((k>>2&7)<<2))
    {
      int row = tid >> 3, k4 = tid & 7;
      float4 v = hg[(size_t)(r0 + row) * 32 + (k0 >> 2) + k4];
      #pragma unroll
      for (int j = 0; j < 4; ++j) {
        int kl = k4 * 4 + j;
        int rsw = row ^ (((kl >> 2) & 7) << 2);
        shT[kl * 32 + rsw] = (&v.x)[j];
      }
    }
    __syncthreads();
    #pragma unroll 8
    for (int kk = 0; kk < 32; ++kk) {
      float4 a4 = *reinterpret_cast<const float4*>(
          &shT[kk * 32 + ((ty ^ ((kk >> 2) & 7)) << 2)]);
      float4 b4 = *reinterpret_cast<const float4*>(&sw[kk * 128 + tx * 4]);
      #pragma unroll
      for (int ri = 0; ri < 4; ++ri) {
        float av = (&a4.x)[ri];
        acc[ri][0] += av * b4.x;
        acc[ri][1] += av * b4.y;
        acc[ri][2] += av * b4.z;
        acc[ri][3] += av * b4.w;
      }
    }
  }

  const int rbase = r0 + ty * 4;
  float4* hp4 = reinterpret_cast<float4*>(hp);
  #pragma unroll
  for (int ri = 0; ri < 4; ++ri) {
    hp4[((size_t)(head * NN + rbase + ri)) * 32 + tx] =
        make_float4(acc[ri][0], acc[ri][1], acc[ri][2], acc[ri][3]);
  }
  float4 As = reinterpret_cast<const float4*>(a_src + head * FF)[tx];
  float4 Ad = reinterpret_cast<const float4*>(a_dst + head * FF)[tx];
  #pragma unroll
  for (int ri = 0; ri < 4; ++ri) {
    float sA = acc[ri][0] * As.x + acc[ri][1] * As.y + acc[ri][2] * As.z +
               acc[ri][3] * As.w;
    float sD = acc[ri][0] * Ad.x + acc[ri][1] * Ad.y + acc[ri][2] * Ad.z +
               acc[ri][3] * Ad.w;
    #pragma unroll
    for (int m = 1; m < 32; m <<= 1) {
      sA += __shfl_xor(sA, m);
      sD += __shfl_xor(sD, m);
    }
    if (tx == 0) {
      attn_src[head * NN + rbase + ri] = sA;
      attn_dst[head * NN + rbase + ri] = sD;
    }
  }
}

// K2: per-head bitonic sort of d = attn_dst ascending, with permutation.
__global__ __launch_bounds__(1024) void k2_sort(
    const float* __restrict__ attn_dst, float* __restrict__ dsort,
    int* __restrict__ permd) {
  __shared__ float key[NN];
  __shared__ int idx[NN];
  const int head = blockIdx.x;
  const int tid = threadIdx.x;
  for (int i = tid; i < NN; i += 1024) {
    key[i] = attn_dst[head * NN + i];
    idx[i] = i;
  }
  __syncthreads();
  for (int k = 2; k <= NN; k <<= 1) {
    for (int j = k >> 1; j > 0; j >>= 1) {
      for (int i = tid; i < NN; i += 1024) {
        int ixj = i ^ j;
        if (ixj > i) {
          float a = key[i], b = key[ixj];
          bool up = ((i & k) == 0);
          if (up ? (a > b) : (a < b)) {
            key[i] = b; key[ixj] = a;
            int t = idx[i]; idx[i] = idx[ixj]; idx[ixj] = t;
          }
        }
      }
      __syncthreads();
    }
  }
  for (int i = tid; i < NN; i += 1024) {
    dsort[head * NN + i] = key[i];
    permd[head * NN + i] = idx[i];
  }
}

// K3: segment sums of e^{0.2d}*hv and e^{d}*hv + scalar z sums.
// 256 threads: feature o = tid&127, jj-half jh = tid>>7 (interleaved jj).
__global__ __launch_bounds__(256) void k3_segsum(
    const float* __restrict__ hp, const float* __restrict__ dsort,
    const int* __restrict__ permd, float* __restrict__ segs,
    float* __restrict__ segz) {
  __shared__ float se0[SEG], se1[SEG];
  __shared__ int sp[SEG];
  __shared__ float comb[2 * FF];
  const int head = blockIdx.y, seg = blockIdx.x;
  const int tid = threadIdx.x;
  const int o = tid & 127, jh = tid >> 7;
  {
    int t = tid & 63;
    float dv = dsort[head * NN + seg * SEG + t];
    if (tid < 64) {
      se0[t] = expf(0.2f * dv);
      sp[t] = permd[head * NN + seg * SEG + t];
    } else if (tid < 128) {
      se1[t] = expf(dv);
    }
  }
  __syncthreads();
  const float* hph = hp + (size_t)head * NN * FF;
  float a0 = 0.f, a1 = 0.f;
  #pragma unroll 8
  for (int u = 0; u < 32; ++u) {
    int jj = u * 2 + jh;
    float hv = hph[(size_t)sp[jj] * FF + o];
    a0 += se0[jj] * hv;
    a1 += se1[jj] * hv;
  }
  if (jh == 1) {
    comb[o] = a0;
    comb[FF + o] = a1;
  }
  __syncthreads();
  if (jh == 0) {
    a0 += comb[o];
    a1 += comb[FF + o];
    size_t base = ((size_t)(head * NSEG + seg)) * 2 * FF;
    segs[base + o] = a0;
    segs[base + FF + o] = a1;
    if (o == 0) {
      float zz0 = 0.f, zz1 = 0.f;
      #pragma unroll
      for (int j = 0; j < SEG; ++j) { zz0 += se0[j]; zz1 += se1[j]; }
      segz[(head * NSEG + seg) * 2 + 0] = zz0;
      segz[(head * NSEG + seg) * 2 + 1] = zz1;
    }
  }
}

// K5: materialize inclusive prefix arrays PF[h][j][2][128] + PFz[h][j][2].
// Checkpoint = inline sum over prior segments' totals (L2-hot, parallel).
__global__ __launch_bounds__(128) void k5_prefix(
    const float* __restrict__ hp, const float* __restrict__ dsort,
    const int* __restrict__ permd, const float* __restrict__ segs,
    const float* __restrict__ segz, float* __restrict__ PF,
    float* __restrict__ PFz) {
  __shared__ float se0[SEG], se1[SEG];
  __shared__ int sp[SEG];
  const int head = blockIdx.y, seg = blockIdx.x;
  const int o = threadIdx.x;
  {
    int t = o & 63;
    float dv = dsort[head * NN + seg * SEG + t];
    if (o < 64) {
      se0[t] = expf(0.2f * dv);
      sp[t] = permd[head * NN + seg * SEG + t];
    } else {
      se1[t] = expf(dv);
    }
  }
  __syncthreads();
  float r0 = 0.f, r1 = 0.f, z0 = 0.f, z1 = 0.f;
  const float* sbase = segs + ((size_t)head * NSEG) * 2 * FF;
  #pragma unroll 4
  for (int k = 0; k < seg; ++k) {
    r0 += sbase[(size_t)k * 2 * FF + o];
    r1 += sbase[(size_t)k * 2 * FF + FF + o];
  }
  #pragma unroll 4
  for (int k = 0; k < seg; ++k) {
    z0 += segz[(head * NSEG + k) * 2 + 0];
    z1 += segz[(head * NSEG + k) * 2 + 1];
  }
  const float* hph = hp + (size_t)head * NN * FF;
  #pragma unroll 4
  for (int jj = 0; jj < SEG; ++jj) {
    int j = seg * SEG + jj;
    float hv = hph[(size_t)sp[jj] * FF + o];
    float e0 = se0[jj], e1 = se1[jj];
    r0 += e0 * hv;
    r1 += e1 * hv;
    z0 += e0;
    z1 += e1;
    size_t pb = ((size_t)(head * NN + j)) * 2 * FF;
    PF[pb + o] = r0;
    PF[pb + FF + o] = r1;
    if (o == 0) {
      PFz[(head * NN + j) * 2 + 0] = z0;
      PFz[(head * NN + j) * 2 + 1] = z1;
    }
  }
}

// K6: 8 parallel binary searches (thread per head), then unrolled per-head
// combine of the two leaky-relu-exp branches; mean over heads + bias.
__global__ __launch_bounds__(128) void k6_out(
    const float* __restrict__ attn_src, const float* __restrict__ dsort,
    const float* __restrict__ PF, const float* __restrict__ PFz,
    const float* __restrict__ bias, float* __restrict__ out) {
  __shared__ int st[NH];
  __shared__ float ss[NH];
  const int n = blockIdx.x, o = threadIdx.x;
  if (o < NH) {
    float s = attn_src[o * NN + n];
    ss[o] = s;
    const float* dp = dsort + o * NN;
    float thr = -s;
    int lo = 0, hi = NN;
    while (lo < hi) {
      int mid = (lo + hi) >> 1;
      if (dp[mid] <= thr) lo = mid + 1; else hi = mid;
    }
    st[o] = lo;  // t = #{d <= -s}: these take the 0.2-slope branch
  }
  __syncthreads();
  float acc = 0.f;
  #pragma unroll
  for (int head = 0; head < NH; ++head) {
    float s = ss[head];
    int t = st[head];
    size_t tb = ((size_t)(head * NN + NN - 1)) * 2 * FF;
    float TotA = PF[tb + FF + o];
    float z1tot = PFz[(head * NN + NN - 1) * 2 + 1];
    float B = 0.f, P1 = 0.f, z0p = 0.f, z1p = 0.f;
    if (t > 0) {
      size_t pb = ((size_t)(head * NN + t - 1)) * 2 * FF;
      B = PF[pb + o];
      P1 = PF[pb + FF + o];
      z0p = PFz[(head * NN + t - 1) * 2 + 0];
      z1p = PFz[(head * NN + t - 1) * 2 + 1];
    }
    float e02s = expf(0.2f * s), es = expf(s);
    float den = e02s * z0p + es * (z1tot - z1p);
    acc += (e02s * B + es * (TotA - P1)) / den;
  }
  out[(size_t)n * FF + o] = 0.125f * acc + bias[o];
}

extern "C" void kernel_launch(void* const* d_in, const int* in_sizes, int n_in,
                              void* d_out, int out_size, void* d_ws,
                              size_t ws_size, hipStream_t stream) {
  const float* h = (const float*)d_in[0];
  const float* w = (const float*)d_in[1];
  const float* a_src = (const float*)d_in[2];
  const float* a_dst = (const float*)d_in[3];
  const float* bias = (const float*)d_in[4];
  float* out = (float*)d_out;

  char* ws = (char*)d_ws;
  size_t off = 0;
  auto alloc = [&](size_t bytes) -> void* {
    void* p = ws + off;
    off += (bytes + 255) & ~(size_t)255;
    return p;
  };
  float* hp = (float*)alloc((size_t)NH * NN * FF * 4);      // 16.8 MB
  float* asrc = (float*)alloc((size_t)NH * NN * 4);
  float* adst = (float*)alloc((size_t)NH * NN * 4);
  float* dsort = (float*)alloc((size_t)NH * NN * 4);
  int* permd = (int*)alloc((size_t)NH * NN * 4);
  float* segs = (float*)alloc((size_t)NH * NSEG * 2 * FF * 4);
  float* segz = (float*)alloc((size_t)NH * NSEG * 2 * 4);
  float* PF = (float*)alloc((size_t)NH * NN * 2 * FF * 4);  // 33.5 MB
  float* PFz = (float*)alloc((size_t)NH * NN * 2 * 4);
  (void)ws_size;  // ~51.5 MB of workspace

  k1_gemm<<<dim3(NN / 32, NH), 256, 0, stream>>>(h, w, a_src, a_dst, hp, asrc,
                                                 adst);
  k2_sort<<<NH, 1024, 0, stream>>>(adst, dsort, permd);
  k3_segsum<<<dim3(NSEG, NH), 256, 0, stream>>>(hp, dsort, permd, segs, segz);
  k5_prefix<<<dim3(NSEG, NH), 128, 0, stream>>>(hp, dsort, permd, segs, segz,
                                                PF, PFz);
  k6_out<<<NN, 128, 0, stream>>>(asrc, dsort, PF, PFz, bias, out);
}

// Round 5
// 161.606 us; speedup vs baseline: 2.0112x; 1.2763x over previous
//
#include <hip/hip_runtime.h>
#include <math.h>

#define NH 8
#define NN 4096
#define FF 128
#define SEG 64
#define NSEG (NN / SEG)  // 64

typedef unsigned long long u64;

// K1: hp[h] = h @ w[h] (fp32, LDS-tiled, 4x4 register tile per thread) with
// fused per-row score dots -> attn_src[h,n], attn_dst[h,n].
__global__ __launch_bounds__(256) void k1_gemm(
    const float* __restrict__ h, const float* __restrict__ w,
    const float* __restrict__ a_src, const float* __restrict__ a_dst,
    float* __restrict__ hp, float* __restrict__ attn_src,
    float* __restrict__ attn_dst) {
  __shared__ float sw[32 * 128];  // w chunk [32 k][128 c]
  __shared__ float shT[32 * 32];  // h chunk transposed [32 k][32 r], XOR-swizzled
  const int head = blockIdx.y;
  const int r0 = blockIdx.x * 32;
  const int tid = threadIdx.x;
  const int ty = tid >> 5;  // 0..7 -> rows ty*4..+3
  const int tx = tid & 31;  // 0..31 -> cols tx*4..+3

  float acc[4][4];
  #pragma unroll
  for (int i = 0; i < 4; ++i)
    #pragma unroll
    for (int j = 0; j < 4; ++j) acc[i][j] = 0.f;

  const float4* wg = reinterpret_cast<const float4*>(w + (size_t)head * 128 * 128);
  const float4* hg = reinterpret_cast<const float4*>(h);

  for (int kc = 0; kc < 4; ++kc) {
    const int k0 = kc * 32;
    __syncthreads();
    #pragma unroll
    for (int it = 0; it < 4; ++it) {
      int q = tid + it * 256;
      int krow = q >> 5, c4 = q & 31;
      float4 v = wg[(size_t)(k0 + krow) * 32 + c4];
      float* dst = &sw[krow * 128 + c4 * 4];
      dst[0] = v.x; dst[1] = v.y; dst[2] = v.z; dst[3] = v.w;
    }
    {
      int row = tid >> 3, k4 = tid & 7;
      float4 v = hg[(size_t)(r0 + row) * 32 + (k0 >> 2) + k4];
      #pragma unroll
      for (int j = 0; j < 4; ++j) {
        int kl = k4 * 4 + j;
        int rsw = row ^ (((kl >> 2) & 7) << 2);
        shT[kl * 32 + rsw] = (&v.x)[j];
      }
    }
    __syncthreads();
    #pragma unroll 8
    for (int kk = 0; kk < 32; ++kk) {
      float4 a4 = *reinterpret_cast<const float4*>(
          &shT[kk * 32 + ((ty ^ ((kk >> 2) & 7)) << 2)]);
      float4 b4 = *reinterpret_cast<const float4*>(&sw[kk * 128 + tx * 4]);
      #pragma unroll
      for (int ri = 0; ri < 4; ++ri) {
        float av = (&a4.x)[ri];
        acc[ri][0] += av * b4.x;
        acc[ri][1] += av * b4.y;
        acc[ri][2] += av * b4.z;
        acc[ri][3] += av * b4.w;
      }
    }
  }

  const int rbase = r0 + ty * 4;
  float4* hp4 = reinterpret_cast<float4*>(hp);
  #pragma unroll
  for (int ri = 0; ri < 4; ++ri) {
    hp4[((size_t)(head * NN + rbase + ri)) * 32 + tx] =
        make_float4(acc[ri][0], acc[ri][1], acc[ri][2], acc[ri][3]);
  }
  float4 As = reinterpret_cast<const float4*>(a_src + head * FF)[tx];
  float4 Ad = reinterpret_cast<const float4*>(a_dst + head * FF)[tx];
  #pragma unroll
  for (int ri = 0; ri < 4; ++ri) {
    float sA = acc[ri][0] * As.x + acc[ri][1] * As.y + acc[ri][2] * As.z +
               acc[ri][3] * As.w;
    float sD = acc[ri][0] * Ad.x + acc[ri][1] * Ad.y + acc[ri][2] * Ad.z +
               acc[ri][3] * Ad.w;
    #pragma unroll
    for (int m = 1; m < 32; m <<= 1) {
      sA += __shfl_xor(sA, m);
      sD += __shfl_xor(sD, m);
    }
    if (tx == 0) {
      attn_src[head * NN + rbase + ri] = sA;
      attn_dst[head * NN + rbase + ri] = sD;
    }
  }
}

// K2a: per (head, 512-chunk): bitonic sort of packed (sortkey32|idx) in LDS.
__global__ __launch_bounds__(256) void k2a_localsort(
    const float* __restrict__ adst, u64* __restrict__ runs) {
  __shared__ u64 sk[512];
  const int head = blockIdx.y, chunk = blockIdx.x, tid = threadIdx.x;
  const int base = head * NN + chunk * 512;
  for (int i = tid; i < 512; i += 256) {
    unsigned ub = __float_as_uint(adst[base + i]);
    unsigned u = (ub & 0x80000000u) ? ~ub : (ub | 0x80000000u);
    sk[i] = ((u64)u << 32) | (unsigned)(chunk * 512 + i);
  }
  __syncthreads();
  for (int k = 2; k <= 512; k <<= 1) {
    for (int j = k >> 1; j > 0; j >>= 1) {
      for (int t = tid; t < 512; t += 256) {
        int ixj = t ^ j;
        if (ixj > t) {
          u64 a = sk[t], b = sk[ixj];
          bool up = ((t & k) == 0);
          if (up ? (a > b) : (a < b)) { sk[t] = b; sk[ixj] = a; }
        }
      }
      __syncthreads();
    }
  }
  for (int i = tid; i < 512; i += 256) runs[base + i] = sk[i];
}

// K2m: merge-path merge of adjacent sorted runs of length L (4 outputs/thread).
template <int L, bool FINAL>
__global__ __launch_bounds__(256) void k2m(
    const u64* __restrict__ src, u64* __restrict__ dst,
    float* __restrict__ dsort, int* __restrict__ permd) {
  const int head = blockIdx.y;
  const int i = (blockIdx.x * 256 + threadIdx.x) * 4;
  const u64* S = src + head * NN;
  const int region = i / (2 * L), q0 = i % (2 * L);
  const u64* A = S + region * 2 * L;
  const u64* B = A + L;
  int lo = q0 > L ? q0 - L : 0, hi = q0 < L ? q0 : L;
  while (lo < hi) {
    int mid = (lo + hi) >> 1;
    if (A[mid] < B[q0 - 1 - mid]) lo = mid + 1; else hi = mid;
  }
  int a = lo, b = q0 - lo;
  #pragma unroll
  for (int t = 0; t < 4; ++t) {
    u64 va = a < L ? A[a] : ~0ULL;
    u64 vb = b < L ? B[b] : ~0ULL;
    u64 v;
    if (va < vb) { v = va; ++a; } else { v = vb; ++b; }
    const int q = region * 2 * L + q0 + t;
    if (FINAL) {
      unsigned u = (unsigned)(v >> 32);
      unsigned ub = (u & 0x80000000u) ? (u ^ 0x80000000u) : ~u;
      dsort[head * NN + q] = __uint_as_float(ub);
      permd[head * NN + q] = (int)(v & 0xffffffffu);
    } else {
      dst[head * NN + q] = v;
    }
  }
}

// K3: segment sums of e^{0.2d}*hv and e^{d}*hv + scalar z sums.
__global__ __launch_bounds__(256) void k3_segsum(
    const float* __restrict__ hp, const float* __restrict__ dsort,
    const int* __restrict__ permd, float* __restrict__ segs,
    float* __restrict__ segz) {
  __shared__ float se0[SEG], se1[SEG];
  __shared__ int sp[SEG];
  __shared__ float comb[2 * FF];
  const int head = blockIdx.y, seg = blockIdx.x;
  const int tid = threadIdx.x;
  const int o = tid & 127, jh = tid >> 7;
  {
    int t = tid & 63;
    float dv = dsort[head * NN + seg * SEG + t];
    if (tid < 64) {
      se0[t] = expf(0.2f * dv);
      sp[t] = permd[head * NN + seg * SEG + t];
    } else if (tid < 128) {
      se1[t] = expf(dv);
    }
  }
  __syncthreads();
  const float* hph = hp + (size_t)head * NN * FF;
  float a0 = 0.f, a1 = 0.f;
  #pragma unroll 8
  for (int u = 0; u < 32; ++u) {
    int jj = u * 2 + jh;
    float hv = hph[(size_t)sp[jj] * FF + o];
    a0 += se0[jj] * hv;
    a1 += se1[jj] * hv;
  }
  if (jh == 1) {
    comb[o] = a0;
    comb[FF + o] = a1;
  }
  __syncthreads();
  if (jh == 0) {
    a0 += comb[o];
    a1 += comb[FF + o];
    size_t base = ((size_t)(head * NSEG + seg)) * 2 * FF;
    segs[base + o] = a0;
    segs[base + FF + o] = a1;
    if (o == 0) {
      float zz0 = 0.f, zz1 = 0.f;
      #pragma unroll
      for (int j = 0; j < SEG; ++j) { zz0 += se0[j]; zz1 += se1[j]; }
      segz[(head * NSEG + seg) * 2 + 0] = zz0;
      segz[(head * NSEG + seg) * 2 + 1] = zz1;
    }
  }
}

// K5: materialize inclusive prefix arrays PF[h][j][2][128] + PFz[h][j][2].
__global__ __launch_bounds__(128) void k5_prefix(
    const float* __restrict__ hp, const float* __restrict__ dsort,
    const int* __restrict__ permd, const float* __restrict__ segs,
    const float* __restrict__ segz, float* __restrict__ PF,
    float* __restrict__ PFz) {
  __shared__ float se0[SEG], se1[SEG];
  __shared__ int sp[SEG];
  const int head = blockIdx.y, seg = blockIdx.x;
  const int o = threadIdx.x;
  {
    int t = o & 63;
    float dv = dsort[head * NN + seg * SEG + t];
    if (o < 64) {
      se0[t] = expf(0.2f * dv);
      sp[t] = permd[head * NN + seg * SEG + t];
    } else {
      se1[t] = expf(dv);
    }
  }
  __syncthreads();
  float r0 = 0.f, r1 = 0.f, z0 = 0.f, z1 = 0.f;
  const float* sbase = segs + ((size_t)head * NSEG) * 2 * FF;
  #pragma unroll 4
  for (int k = 0; k < seg; ++k) {
    r0 += sbase[(size_t)k * 2 * FF + o];
    r1 += sbase[(size_t)k * 2 * FF + FF + o];
  }
  #pragma unroll 4
  for (int k = 0; k < seg; ++k) {
    z0 += segz[(head * NSEG + k) * 2 + 0];
    z1 += segz[(head * NSEG + k) * 2 + 1];
  }
  const float* hph = hp + (size_t)head * NN * FF;
  #pragma unroll 4
  for (int jj = 0; jj < SEG; ++jj) {
    int j = seg * SEG + jj;
    float hv = hph[(size_t)sp[jj] * FF + o];
    float e0 = se0[jj], e1 = se1[jj];
    r0 += e0 * hv;
    r1 += e1 * hv;
    z0 += e0;
    z1 += e1;
    size_t pb = ((size_t)(head * NN + j)) * 2 * FF;
    PF[pb + o] = r0;
    PF[pb + FF + o] = r1;
    if (o == 0) {
      PFz[(head * NN + j) * 2 + 0] = z0;
      PFz[(head * NN + j) * 2 + 1] = z1;
    }
  }
}

// K6: 8 parallel binary searches (thread per head), then per-head combine.
__global__ __launch_bounds__(128) void k6_out(
    const float* __restrict__ attn_src, const float* __restrict__ dsort,
    const float* __restrict__ PF, const float* __restrict__ PFz,
    const float* __restrict__ bias, float* __restrict__ out) {
  __shared__ int st[NH];
  __shared__ float ss[NH];
  const int n = blockIdx.x, o = threadIdx.x;
  if (o < NH) {
    float s = attn_src[o * NN + n];
    ss[o] = s;
    const float* dp = dsort + o * NN;
    float thr = -s;
    int lo = 0, hi = NN;
    while (lo < hi) {
      int mid = (lo + hi) >> 1;
      if (dp[mid] <= thr) lo = mid + 1; else hi = mid;
    }
    st[o] = lo;  // t = #{d <= -s}: these take the 0.2-slope branch
  }
  __syncthreads();
  float acc = 0.f;
  #pragma unroll
  for (int head = 0; head < NH; ++head) {
    float s = ss[head];
    int t = st[head];
    size_t tb = ((size_t)(head * NN + NN - 1)) * 2 * FF;
    float TotA = PF[tb + FF + o];
    float z1tot = PFz[(head * NN + NN - 1) * 2 + 1];
    float B = 0.f, P1 = 0.f, z0p = 0.f, z1p = 0.f;
    if (t > 0) {
      size_t pb = ((size_t)(head * NN + t - 1)) * 2 * FF;
      B = PF[pb + o];
      P1 = PF[pb + FF + o];
      z0p = PFz[(head * NN + t - 1) * 2 + 0];
      z1p = PFz[(head * NN + t - 1) * 2 + 1];
    }
    float e02s = expf(0.2f * s), es = expf(s);
    float den = e02s * z0p + es * (z1tot - z1p);
    acc += (e02s * B + es * (TotA - P1)) / den;
  }
  out[(size_t)n * FF + o] = 0.125f * acc + bias[o];
}

extern "C" void kernel_launch(void* const* d_in, const int* in_sizes, int n_in,
                              void* d_out, int out_size, void* d_ws,
                              size_t ws_size, hipStream_t stream) {
  const float* h = (const float*)d_in[0];
  const float* w = (const float*)d_in[1];
  const float* a_src = (const float*)d_in[2];
  const float* a_dst = (const float*)d_in[3];
  const float* bias = (const float*)d_in[4];
  float* out = (float*)d_out;

  char* ws = (char*)d_ws;
  size_t off = 0;
  auto alloc = [&](size_t bytes) -> void* {
    void* p = ws + off;
    off += (bytes + 255) & ~(size_t)255;
    return p;
  };
  float* hp = (float*)alloc((size_t)NH * NN * FF * 4);      // 16.8 MB
  float* asrc = (float*)alloc((size_t)NH * NN * 4);
  float* adst = (float*)alloc((size_t)NH * NN * 4);
  float* dsort = (float*)alloc((size_t)NH * NN * 4);
  int* permd = (int*)alloc((size_t)NH * NN * 4);
  float* segs = (float*)alloc((size_t)NH * NSEG * 2 * FF * 4);
  float* segz = (float*)alloc((size_t)NH * NSEG * 2 * 4);
  float* PF = (float*)alloc((size_t)NH * NN * 2 * FF * 4);  // 33.5 MB
  float* PFz = (float*)alloc((size_t)NH * NN * 2 * 4);
  u64* sbuf0 = (u64*)alloc((size_t)NH * NN * 8);            // 256 KB
  u64* sbuf1 = (u64*)alloc((size_t)NH * NN * 8);            // 256 KB
  (void)ws_size;  // ~52 MB of workspace

  k1_gemm<<<dim3(NN / 32, NH), 256, 0, stream>>>(h, w, a_src, a_dst, hp, asrc,
                                                 adst);
  k2a_localsort<<<dim3(8, NH), 256, 0, stream>>>(adst, sbuf0);
  k2m<512, false><<<dim3(4, NH), 256, 0, stream>>>(sbuf0, sbuf1, nullptr,
                                                   nullptr);
  k2m<1024, false><<<dim3(4, NH), 256, 0, stream>>>(sbuf1, sbuf0, nullptr,
                                                    nullptr);
  k2m<2048, true><<<dim3(4, NH), 256, 0, stream>>>(sbuf0, nullptr, dsort,
                                                   permd);
  k3_segsum<<<dim3(NSEG, NH), 256, 0, stream>>>(hp, dsort, permd, segs, segz);
  k5_prefix<<<dim3(NSEG, NH), 128, 0, stream>>>(hp, dsort, permd, segs, segz,
                                                PF, PFz);
  k6_out<<<NN, 128, 0, stream>>>(asrc, dsort, PF, PFz, bias, out);
}